// Round 1
// baseline (842.838 us; speedup 1.0000x reference)
//
#include <hip/hip_runtime.h>
#include <stdint.h>

// ---------- problem constants ----------
constexpr int NN = 100000;   // nodes
constexpr int NE = 1600000;  // edges
constexpr int DIN = 165;     // input feat
// H = 128

typedef __attribute__((ext_vector_type(8))) short bh8;           // 8 x bf16 bits
typedef __attribute__((ext_vector_type(4))) float f4;            // mfma acc
typedef __attribute__((ext_vector_type(4))) unsigned short us4;  // 4 x bf16 bits

__device__ inline unsigned short f2bf(float x) {
  union { float f; uint32_t u; } un; un.f = x;
  uint32_t u = un.u;
  return (unsigned short)((u + 0x7FFFu + ((u >> 16) & 1u)) >> 16);  // RNE
}

// ---------- workspace byte offsets ----------
constexpr size_t OFF_DEG    = 0;                          // int[NN]           (zeroed)
constexpr size_t OFF_STATS  = 400128;                     // float[5*64*256]   (zeroed)
constexpr size_t ZERO_BYTES = OFF_STATS + (size_t)5*64*256*4;          // 727808
constexpr size_t OFF_ROWPTR = ZERO_BYTES;                 // int[NN]
constexpr size_t OFF_FILLP  = OFF_ROWPTR + 400128;
constexpr size_t OFF_DINV   = OFF_FILLP + 400128;         // float[NN]
constexpr size_t OFF_BLK    = OFF_DINV + 400128;          // int[512]
constexpr size_t OFF_SS     = OFF_BLK + 2048;             // float[5*256] scale/shift
constexpr size_t OFF_W1T    = OFF_SS + 5*256*4;           // bf16 [128][192]
constexpr size_t OFF_W2T    = OFF_W1T + 128*192*2;        // bf16 [128][128]
constexpr size_t OFF_FW1T   = OFF_W2T + 128*128*2;        // bf16 [128][128]
constexpr size_t OFF_FW2T   = OFF_FW1T + 128*128*2;       // bf16 [64][128]
constexpr size_t OFF_FW3T   = OFF_FW2T + 64*128*2;        // bf16 [64][64]
constexpr size_t OFF_BW1T   = OFF_FW3T + 64*64*2;         // bf16 [64][128]
constexpr size_t OFF_BW2T   = OFF_BW1T + 64*128*2;        // bf16 [16][64]
constexpr size_t OFF_COL    = (OFF_BW2T + 16*64*2 + 255) & ~(size_t)255;  // int[NE]
constexpr size_t OFF_BUF0   = (OFF_COL + (size_t)NE*4 + 255) & ~(size_t)255; // float[NN*128]
constexpr size_t OFF_BUF1   = OFF_BUF0 + (size_t)NN*128*4;                   // float[NN*128]

constexpr int NBS = (NN + 255) / 256;  // 391 scan blocks

// ---------- CSR build ----------
__global__ __launch_bounds__(256) void k_hist(const int* __restrict__ dst, int* __restrict__ deg) {
  int e = blockIdx.x * 256 + threadIdx.x;
  if (e < NE) atomicAdd(&deg[dst[e]], 1);
}

__global__ __launch_bounds__(256) void k_scan1(const int* __restrict__ deg, int* __restrict__ bsum) {
  __shared__ int sh[256];
  int i = blockIdx.x * 256 + threadIdx.x;
  sh[threadIdx.x] = (i < NN) ? deg[i] : 0;
  __syncthreads();
  for (int o = 128; o > 0; o >>= 1) {
    if (threadIdx.x < o) sh[threadIdx.x] += sh[threadIdx.x + o];
    __syncthreads();
  }
  if (threadIdx.x == 0) bsum[blockIdx.x] = sh[0];
}

__global__ __launch_bounds__(512) void k_scan2(int* __restrict__ bsum) {
  __shared__ int sh[512];
  int t = threadIdx.x;
  int v = (t < NBS) ? bsum[t] : 0;
  sh[t] = v; __syncthreads();
  for (int o = 1; o < 512; o <<= 1) {
    int x = (t >= o) ? sh[t - o] : 0;
    __syncthreads();
    sh[t] += x;
    __syncthreads();
  }
  if (t < NBS) bsum[t] = sh[t] - v;  // exclusive block offsets
}

__global__ __launch_bounds__(256) void k_scan3(const int* __restrict__ deg, const int* __restrict__ boff,
                                               int* __restrict__ rowptr, int* __restrict__ fillptr,
                                               float* __restrict__ dinv) {
  __shared__ int sh[256];
  int t = threadIdx.x, i = blockIdx.x * 256 + t;
  int v = (i < NN) ? deg[i] : 0;
  sh[t] = v; __syncthreads();
  for (int o = 1; o < 256; o <<= 1) {
    int x = (t >= o) ? sh[t - o] : 0;
    __syncthreads();
    sh[t] += x;
    __syncthreads();
  }
  if (i < NN) {
    int excl = sh[t] - v + boff[blockIdx.x];
    rowptr[i] = excl; fillptr[i] = excl;
    dinv[i] = rsqrtf((float)(v + 1));  // +1 self-loop; deg>=1 always
  }
}

__global__ __launch_bounds__(256) void k_fill(const int* __restrict__ srcv, const int* __restrict__ dstv,
                                              int* __restrict__ fillptr, int* __restrict__ colv) {
  int e = blockIdx.x * 256 + threadIdx.x;
  if (e < NE) {
    int p = atomicAdd(&fillptr[dstv[e]], 1);
    colv[p] = srcv[e];
  }
}

// ---------- weight prep: W[K,C] fp32 -> WT[Cpad][Kpad] bf16 (zero-padded) ----------
__global__ __launch_bounds__(256) void k_wprep(const float* __restrict__ W1, const float* __restrict__ W2,
                                               const float* __restrict__ fW1, const float* __restrict__ fW2,
                                               const float* __restrict__ fW3, const float* __restrict__ bW1,
                                               const float* __restrict__ bW2, char* __restrict__ wsb) {
  int b = blockIdx.x, t = threadIdx.x;
  const float* src; unsigned short* dst; int K, C, Kpad, base;
  if (b < 96)       { src = W1;  dst = (unsigned short*)(wsb + OFF_W1T);  K = DIN; C = 128; Kpad = 192; base = b; }
  else if (b < 160) { src = W2;  dst = (unsigned short*)(wsb + OFF_W2T);  K = 128; C = 128; Kpad = 128; base = b - 96; }
  else if (b < 224) { src = fW1; dst = (unsigned short*)(wsb + OFF_FW1T); K = 128; C = 128; Kpad = 128; base = b - 160; }
  else if (b < 256) { src = fW2; dst = (unsigned short*)(wsb + OFF_FW2T); K = 128; C = 64;  Kpad = 128; base = b - 224; }
  else if (b < 272) { src = fW3; dst = (unsigned short*)(wsb + OFF_FW3T); K = 64;  C = 50;  Kpad = 64;  base = b - 256; }
  else if (b < 304) { src = bW1; dst = (unsigned short*)(wsb + OFF_BW1T); K = 128; C = 64;  Kpad = 128; base = b - 272; }
  else              { src = bW2; dst = (unsigned short*)(wsb + OFF_BW2T); K = 64;  C = 3;   Kpad = 64;  base = b - 304; }
  int idx = base * 256 + t;
  int c = idx / Kpad, k = idx - c * Kpad;
  float v = (c < C && k < K) ? src[k * C + c] : 0.f;
  dst[idx] = f2bf(v);
}

// ---------- fused GEMM: out[N,C] = pre(in[N,K]) @ W[K,C] (+bias) (+BN-stat accum) ----------
// pre = identity (ss==null) or relu(in*scale[k]+shift[k]).
// A frag: row=lane&15, k=8*(lane>>4)+i ; B frag from WT[c][k]; D: col=lane&15, row=4*(lane>>4)+reg.
template <int KPAD, int CPAD>
__global__ __launch_bounds__(256) void k_gemm(const float* __restrict__ in, int K, int C,
                                              const float* __restrict__ ss,
                                              const unsigned short* __restrict__ WT,
                                              const float* __restrict__ bias,
                                              float* __restrict__ out, float* __restrict__ stats) {
  constexpr int KL = KPAD + 8;        // LDS row pad (bank spread)
  constexpr int NCT = CPAD / 16;
  __shared__ __attribute__((aligned(16))) unsigned short Alds[64 * KL];
  __shared__ float s_sum[128], s_sq[128];
  int tid = threadIdx.x;
  int rowbase = blockIdx.x * 64;
  if (stats && tid < 128) { s_sum[tid] = 0.f; s_sq[tid] = 0.f; }

  if (K == KPAD && (KPAD % 4) == 0) {  // vector staging
    for (int idx4 = tid; idx4 < 64 * KPAD / 4; idx4 += 256) {
      int r = idx4 / (KPAD / 4);
      int k = (idx4 - r * (KPAD / 4)) * 4;
      int gr = rowbase + r;
      float4 v = make_float4(0.f, 0.f, 0.f, 0.f);
      if (gr < NN) v = *(const float4*)(in + (size_t)gr * K + k);
      if (ss) {
        v.x = fmaxf(fmaf(v.x, ss[k],     ss[128 + k]),     0.f);
        v.y = fmaxf(fmaf(v.y, ss[k + 1], ss[129 + k]),     0.f);
        v.z = fmaxf(fmaf(v.z, ss[k + 2], ss[130 + k]),     0.f);
        v.w = fmaxf(fmaf(v.w, ss[k + 3], ss[131 + k]),     0.f);
      }
      us4 o = { f2bf(v.x), f2bf(v.y), f2bf(v.z), f2bf(v.w) };
      *(us4*)&Alds[r * KL + k] = o;
    }
  } else {  // scalar staging (K=165 -> KPAD=192, zero pad)
    for (int idx = tid; idx < 64 * KPAD; idx += 256) {
      int r = idx / KPAD, k = idx - r * KPAD;
      int gr = rowbase + r;
      float v = 0.f;
      if (gr < NN && k < K) {
        v = in[(size_t)gr * K + k];
        if (ss) v = fmaxf(fmaf(v, ss[k], ss[128 + k]), 0.f);
      }
      Alds[r * KL + k] = f2bf(v);
    }
  }
  __syncthreads();

  int lane = tid & 63, wave = tid >> 6;
  int lr = lane & 15, lk = (lane >> 4) * 8;
  f4 acc[NCT] = {};
  for (int kt = 0; kt < KPAD / 32; ++kt) {
    bh8 a = *(const bh8*)&Alds[(wave * 16 + lr) * KL + kt * 32 + lk];
#pragma unroll
    for (int ct = 0; ct < NCT; ++ct) {
      bh8 b = *(const bh8*)&WT[(ct * 16 + lr) * KPAD + kt * 32 + lk];
      acc[ct] = __builtin_amdgcn_mfma_f32_16x16x32_bf16(a, b, acc[ct], 0, 0, 0);
    }
  }

  int r0 = rowbase + wave * 16 + (lane >> 4) * 4;
#pragma unroll
  for (int ct = 0; ct < NCT; ++ct) {
    int c = ct * 16 + lr;
    float bv = (bias != nullptr && c < C) ? bias[c] : 0.f;
    float cs = 0.f, cq = 0.f;
#pragma unroll
    for (int rg = 0; rg < 4; ++rg) {
      int gr = r0 + rg;
      if (gr < NN && c < C) {
        float v = acc[ct][rg] + bv;
        out[(size_t)gr * C + c] = v;
        cs += v; cq += v * v;
      }
    }
    if (stats && c < C) { atomicAdd(&s_sum[c], cs); atomicAdd(&s_sq[c], cq); }
  }
  if (stats) {
    __syncthreads();
    int slot = blockIdx.x & 63;
    if (tid < 128) {
      atomicAdd(&stats[slot * 256 + tid], s_sum[tid]);
      atomicAdd(&stats[slot * 256 + 128 + tid], s_sq[tid]);
    }
  }
}

// ---------- GCN aggregation: out[i] = dinv_i^2*t[i] + sum_e dinv[src]*dinv_i*t[src], + BN stats ----------
__global__ __launch_bounds__(256) void k_agg(const float* __restrict__ t, const int* __restrict__ colv,
                                             const int* __restrict__ rowptr, const int* __restrict__ deg,
                                             const float* __restrict__ dinv, float* __restrict__ out,
                                             float* __restrict__ stats) {
  __shared__ float rs[4][128], rq[4][128];
  int lane = threadIdx.x & 63, wave = threadIdx.x >> 6;
  int node = blockIdx.x * 4 + wave;
  float a0 = 0.f, a1 = 0.f;
  if (node < NN) {
    float di = dinv[node];
    float2 sv = *(const float2*)(t + (size_t)node * 128 + lane * 2);
    a0 = di * di * sv.x; a1 = di * di * sv.y;
    int start = rowptr[node], len = deg[node];
    for (int j0 = 0; j0 < len; j0 += 64) {
      int cnt = min(len - j0, 64);
      int id = 0; float dv = 0.f;
      if (lane < cnt) { id = colv[start + j0 + lane]; dv = dinv[id]; }
      for (int j = 0; j < cnt; ++j) {
        int s = __shfl(id, j);
        float coef = __shfl(dv, j) * di;
        float2 v = *(const float2*)(t + (size_t)s * 128 + lane * 2);
        a0 = fmaf(coef, v.x, a0);
        a1 = fmaf(coef, v.y, a1);
      }
    }
    *(float2*)(out + (size_t)node * 128 + lane * 2) = make_float2(a0, a1);
  }
  rs[wave][lane * 2] = a0; rs[wave][lane * 2 + 1] = a1;
  rq[wave][lane * 2] = a0 * a0; rq[wave][lane * 2 + 1] = a1 * a1;
  __syncthreads();
  if (threadIdx.x < 128) {
    int c = threadIdx.x;
    float s = rs[0][c] + rs[1][c] + rs[2][c] + rs[3][c];
    float q = rq[0][c] + rq[1][c] + rq[2][c] + rq[3][c];
    int slot = blockIdx.x & 63;
    atomicAdd(&stats[slot * 256 + c], s);
    atomicAdd(&stats[slot * 256 + 128 + c], q);
  }
}

// ---------- BN finalize: (sum,sumsq,g,be) -> scale/shift ----------
__global__ __launch_bounds__(128) void k_finalize(const float* __restrict__ stats, const float* __restrict__ g,
                                                  const float* __restrict__ be, float* __restrict__ ssout, int C) {
  int c = threadIdx.x;
  if (c < C) {
    float s = 0.f, q = 0.f;
    for (int k = 0; k < 64; ++k) { s += stats[k * 256 + c]; q += stats[k * 256 + 128 + c]; }
    const float invN = 1.f / (float)NN;
    float mean = s * invN;
    float var = fmaxf(q * invN - mean * mean, 0.f);
    float scale = g[c] * rsqrtf(var + 1e-5f);
    ssout[c] = scale;
    ssout[128 + c] = be[c] - mean * scale;
  }
}

// ---------- emb = relu(bn(a2)) -> d_out ----------
__global__ __launch_bounds__(256) void k_embwrite(const float* __restrict__ a2, const float* __restrict__ ss,
                                                  float* __restrict__ emb) {
  int idx = blockIdx.x * 256 + threadIdx.x;  // one float4 per thread
  if (idx < NN * 32) {
    int cb = (idx & 31) * 4;
    float4 v = *(const float4*)(a2 + (size_t)idx * 4);
    float4 o;
    o.x = fmaxf(fmaf(v.x, ss[cb],     ss[128 + cb]), 0.f);
    o.y = fmaxf(fmaf(v.y, ss[cb + 1], ss[129 + cb]), 0.f);
    o.z = fmaxf(fmaf(v.z, ss[cb + 2], ss[130 + cb]), 0.f);
    o.w = fmaxf(fmaf(v.w, ss[cb + 3], ss[131 + cb]), 0.f);
    *(float4*)(emb + (size_t)idx * 4) = o;
  }
}

extern "C" void kernel_launch(void* const* d_in, const int* in_sizes, int n_in,
                              void* d_out, int out_size, void* d_ws, size_t ws_size,
                              hipStream_t stream) {
  (void)in_sizes; (void)n_in; (void)out_size; (void)ws_size;
  const float* x   = (const float*)d_in[0];
  const int*   ei  = (const int*)d_in[1];
  const float* W1  = (const float*)d_in[2];
  const float* W2  = (const float*)d_in[4];
  const float* g1  = (const float*)d_in[6];
  const float* be1 = (const float*)d_in[7];
  const float* g2  = (const float*)d_in[8];
  const float* be2 = (const float*)d_in[9];
  const float* fW1 = (const float*)d_in[10];
  const float* fg1 = (const float*)d_in[12];
  const float* fbe1= (const float*)d_in[13];
  const float* fW2 = (const float*)d_in[14];
  const float* fg2 = (const float*)d_in[16];
  const float* fbe2= (const float*)d_in[17];
  const float* fW3 = (const float*)d_in[18];
  const float* fb3 = (const float*)d_in[19];
  const float* bW1 = (const float*)d_in[20];
  const float* bg1 = (const float*)d_in[22];
  const float* bbe1= (const float*)d_in[23];
  const float* bW2 = (const float*)d_in[24];
  const float* bb2 = (const float*)d_in[25];

  float* outp = (float*)d_out;
  float* fl  = outp;                       // [NN,50]
  float* bl  = outp + (size_t)NN * 50;     // [NN,3]
  float* emb = outp + (size_t)NN * 53;     // [NN,128]

  char* wsb = (char*)d_ws;
  int*   deg    = (int*)(wsb + OFF_DEG);
  float* stats  = (float*)(wsb + OFF_STATS);
  int*   rowptr = (int*)(wsb + OFF_ROWPTR);
  int*   fillp  = (int*)(wsb + OFF_FILLP);
  float* dinv   = (float*)(wsb + OFF_DINV);
  int*   blk    = (int*)(wsb + OFF_BLK);
  float* ssb    = (float*)(wsb + OFF_SS);
  const unsigned short* W1T  = (const unsigned short*)(wsb + OFF_W1T);
  const unsigned short* W2T  = (const unsigned short*)(wsb + OFF_W2T);
  const unsigned short* FW1T = (const unsigned short*)(wsb + OFF_FW1T);
  const unsigned short* FW2T = (const unsigned short*)(wsb + OFF_FW2T);
  const unsigned short* FW3T = (const unsigned short*)(wsb + OFF_FW3T);
  const unsigned short* BW1T = (const unsigned short*)(wsb + OFF_BW1T);
  const unsigned short* BW2T = (const unsigned short*)(wsb + OFF_BW2T);
  int*   colv   = (int*)(wsb + OFF_COL);
  float* buf0   = (float*)(wsb + OFF_BUF0);
  float* buf1   = (float*)(wsb + OFF_BUF1);

  const int GE = (NE + 255) / 256;     // 6250
  const int GG = (NN + 63) / 64;       // 1563
  const int GA = (NN + 3) / 4;         // 25000

  hipMemsetAsync(d_ws, 0, ZERO_BYTES, stream);  // deg + stats slots

  // CSR (dst-major) + dinv
  k_hist <<<GE, 256, 0, stream>>>(ei + NE, deg);
  k_scan1<<<NBS, 256, 0, stream>>>(deg, blk);
  k_scan2<<<1, 512, 0, stream>>>(blk);
  k_scan3<<<NBS, 256, 0, stream>>>(deg, blk, rowptr, fillp, dinv);
  k_fill <<<GE, 256, 0, stream>>>(ei, ei + NE, fillp, colv);
  k_wprep<<<308, 256, 0, stream>>>(W1, W2, fW1, fW2, fW3, bW1, bW2, wsb);

  // GCN layer 1: t1 = x@W1 ; a1 = A_hat t1 ; bn1
  k_gemm<192, 128><<<GG, 256, 0, stream>>>(x, DIN, 128, nullptr, W1T, nullptr, buf0, nullptr);
  k_agg<<<GA, 256, 0, stream>>>(buf0, colv, rowptr, deg, dinv, buf1, stats + 0 * 16384);
  k_finalize<<<1, 128, 0, stream>>>(stats + 0 * 16384, g1, be1, ssb + 0 * 256, 128);

  // GCN layer 2: t2 = relu(bn1(a1))@W2 ; a2 = A_hat t2 ; bn2
  k_gemm<128, 128><<<GG, 256, 0, stream>>>(buf1, 128, 128, ssb + 0 * 256, W2T, nullptr, buf0, nullptr);
  k_agg<<<GA, 256, 0, stream>>>(buf0, colv, rowptr, deg, dinv, buf1, stats + 1 * 16384);
  k_finalize<<<1, 128, 0, stream>>>(stats + 1 * 16384, g2, be2, ssb + 1 * 256, 128);

  // emb = relu(bn2(a2))
  k_embwrite<<<NN * 32 / 256, 256, 0, stream>>>(buf1, ssb + 1 * 256, emb);

  // forward head
  k_gemm<128, 128><<<GG, 256, 0, stream>>>(emb, 128, 128, nullptr, FW1T, nullptr, buf0, stats + 2 * 16384);
  k_finalize<<<1, 128, 0, stream>>>(stats + 2 * 16384, fg1, fbe1, ssb + 2 * 256, 128);
  k_gemm<128, 64><<<GG, 256, 0, stream>>>(buf0, 128, 64, ssb + 2 * 256, FW2T, nullptr, buf1, stats + 3 * 16384);
  k_finalize<<<1, 128, 0, stream>>>(stats + 3 * 16384, fg2, fbe2, ssb + 3 * 256, 64);
  k_gemm<64, 64><<<GG, 256, 0, stream>>>(buf1, 64, 50, ssb + 3 * 256, FW3T, fb3, fl, nullptr);

  // backward head
  k_gemm<128, 64><<<GG, 256, 0, stream>>>(emb, 128, 64, nullptr, BW1T, nullptr, buf1 + (size_t)NN * 64, stats + 4 * 16384);
  k_finalize<<<1, 128, 0, stream>>>(stats + 4 * 16384, bg1, bbe1, ssb + 4 * 256, 64);
  k_gemm<64, 16><<<GG, 256, 0, stream>>>(buf1 + (size_t)NN * 64, 64, 3, ssb + 4 * 256, BW2T, bb2, bl, nullptr);
}

// Round 2
// 679.982 us; speedup vs baseline: 1.2395x; 1.2395x over previous
//
#include <hip/hip_runtime.h>
#include <stdint.h>

// ---------- problem constants ----------
constexpr int NN = 100000;   // nodes
constexpr int NE = 1600000;  // edges
constexpr int DIN = 165;     // input feat

typedef __attribute__((ext_vector_type(8))) short bh8;   // 8 x bf16 bits
typedef __attribute__((ext_vector_type(4))) float f4;    // mfma acc

__device__ inline unsigned short f2bf(float x) {
  union { float f; uint32_t u; } un; un.f = x;
  uint32_t u = un.u;
  return (unsigned short)((u + 0x7FFFu + ((u >> 16) & 1u)) >> 16);  // RNE
}
__device__ inline float bf2f(unsigned short u) {
  union { uint32_t i; float f; } c; c.i = (uint32_t)u << 16; return c.f;
}
__device__ inline float bflo(uint32_t v) {
  union { uint32_t i; float f; } c; c.i = v << 16; return c.f;
}
__device__ inline float bfhi(uint32_t v) {
  union { uint32_t i; float f; } c; c.i = v & 0xffff0000u; return c.f;
}

// ---------- workspace byte offsets ----------
constexpr size_t OFF_DEG    = 0;                          // int[NN]            (zeroed)
constexpr size_t OFF_STATS  = 400128;                     // float[5*64*256]    (zeroed)
constexpr size_t ZERO_BYTES = OFF_STATS + (size_t)5*64*256*4;   // 727808
constexpr size_t OFF_ROWPTR = ZERO_BYTES;                 // int[NN]
constexpr size_t OFF_FILLP  = OFF_ROWPTR + 400128;
constexpr size_t OFF_DINV   = OFF_FILLP + 400128;         // float[NN]
constexpr size_t OFF_BLK    = OFF_DINV + 400128;          // int[512]
constexpr size_t OFF_SS     = OFF_BLK + 2048;             // float[5*256] scale/shift
constexpr size_t OFF_W1T    = OFF_SS + 5*256*4;           // bf16 [128][192]
constexpr size_t OFF_W2T    = OFF_W1T + 128*192*2;        // bf16 [128][128]
constexpr size_t OFF_FW1T   = OFF_W2T + 128*128*2;        // bf16 [128][128]
constexpr size_t OFF_FW2T   = OFF_FW1T + 128*128*2;       // bf16 [64][128]
constexpr size_t OFF_FW3T   = OFF_FW2T + 64*128*2;        // bf16 [64][64]
constexpr size_t OFF_BW1T   = OFF_FW3T + 64*64*2;         // bf16 [64][128]
constexpr size_t OFF_BW2T   = OFF_BW1T + 64*128*2;        // bf16 [16][64]
constexpr size_t OFF_COL    = (OFF_BW2T + 16*64*2 + 255) & ~(size_t)255;      // int[NE]
constexpr size_t OFF_BUF0   = (OFF_COL + (size_t)NE*4 + 255) & ~(size_t)255;  // bf16[NN*128]
constexpr size_t OFF_BUF1   = OFF_BUF0 + (size_t)NN*128*2;                    // bf16[NN*128]
constexpr size_t OFF_BUF2   = OFF_BUF1 + (size_t)NN*128*2;                    // bf16[NN*128]

constexpr int NBS = (NN + 255) / 256;  // 391 scan blocks

// ---------- CSR build ----------
__global__ __launch_bounds__(256) void k_hist(const int* __restrict__ dst, int* __restrict__ deg) {
  int e = blockIdx.x * 256 + threadIdx.x;
  if (e < NE) atomicAdd(&deg[dst[e]], 1);
}

__global__ __launch_bounds__(256) void k_scan1(const int* __restrict__ deg, int* __restrict__ bsum) {
  __shared__ int sh[256];
  int i = blockIdx.x * 256 + threadIdx.x;
  sh[threadIdx.x] = (i < NN) ? deg[i] : 0;
  __syncthreads();
  for (int o = 128; o > 0; o >>= 1) {
    if (threadIdx.x < o) sh[threadIdx.x] += sh[threadIdx.x + o];
    __syncthreads();
  }
  if (threadIdx.x == 0) bsum[blockIdx.x] = sh[0];
}

__global__ __launch_bounds__(512) void k_scan2(int* __restrict__ bsum) {
  __shared__ int sh[512];
  int t = threadIdx.x;
  int v = (t < NBS) ? bsum[t] : 0;
  sh[t] = v; __syncthreads();
  for (int o = 1; o < 512; o <<= 1) {
    int x = (t >= o) ? sh[t - o] : 0;
    __syncthreads();
    sh[t] += x;
    __syncthreads();
  }
  if (t < NBS) bsum[t] = sh[t] - v;  // exclusive block offsets
}

__global__ __launch_bounds__(256) void k_scan3(const int* __restrict__ deg, const int* __restrict__ boff,
                                               int* __restrict__ rowptr, int* __restrict__ fillptr,
                                               float* __restrict__ dinv) {
  __shared__ int sh[256];
  int t = threadIdx.x, i = blockIdx.x * 256 + t;
  int v = (i < NN) ? deg[i] : 0;
  sh[t] = v; __syncthreads();
  for (int o = 1; o < 256; o <<= 1) {
    int x = (t >= o) ? sh[t - o] : 0;
    __syncthreads();
    sh[t] += x;
    __syncthreads();
  }
  if (i < NN) {
    int excl = sh[t] - v + boff[blockIdx.x];
    rowptr[i] = excl; fillptr[i] = excl;
    dinv[i] = rsqrtf((float)(v + 1));  // +1 self-loop
  }
}

__global__ __launch_bounds__(256) void k_fill(const int* __restrict__ srcv, const int* __restrict__ dstv,
                                              int* __restrict__ fillptr, int* __restrict__ colv) {
  int e = blockIdx.x * 256 + threadIdx.x;
  if (e < NE) {
    int p = atomicAdd(&fillptr[dstv[e]], 1);
    colv[p] = srcv[e];
  }
}

// ---------- weight prep: W[K,C] fp32 -> WT[Cpad][Kpad] bf16 ----------
__global__ __launch_bounds__(256) void k_wprep(const float* __restrict__ W1, const float* __restrict__ W2,
                                               const float* __restrict__ fW1, const float* __restrict__ fW2,
                                               const float* __restrict__ fW3, const float* __restrict__ bW1,
                                               const float* __restrict__ bW2, char* __restrict__ wsb) {
  int b = blockIdx.x, t = threadIdx.x;
  const float* src; unsigned short* dst; int K, C, Kpad, base;
  if (b < 96)       { src = W1;  dst = (unsigned short*)(wsb + OFF_W1T);  K = DIN; C = 128; Kpad = 192; base = b; }
  else if (b < 160) { src = W2;  dst = (unsigned short*)(wsb + OFF_W2T);  K = 128; C = 128; Kpad = 128; base = b - 96; }
  else if (b < 224) { src = fW1; dst = (unsigned short*)(wsb + OFF_FW1T); K = 128; C = 128; Kpad = 128; base = b - 160; }
  else if (b < 256) { src = fW2; dst = (unsigned short*)(wsb + OFF_FW2T); K = 128; C = 64;  Kpad = 128; base = b - 224; }
  else if (b < 272) { src = fW3; dst = (unsigned short*)(wsb + OFF_FW3T); K = 64;  C = 50;  Kpad = 64;  base = b - 256; }
  else if (b < 304) { src = bW1; dst = (unsigned short*)(wsb + OFF_BW1T); K = 128; C = 64;  Kpad = 128; base = b - 272; }
  else              { src = bW2; dst = (unsigned short*)(wsb + OFF_BW2T); K = 64;  C = 3;   Kpad = 64;  base = b - 304; }
  int idx = base * 256 + t;
  int c = idx / Kpad, k = idx - c * Kpad;
  float v = (c < C && k < K) ? src[k * C + c] : 0.f;
  dst[idx] = f2bf(v);
}

// ---------- fused GEMM: out[N,C] = pre(in[N,K]) @ W[K,C] (+bias) (+BN stats) ----------
// pre = identity (ss==null) or relu(in*scale[k]+shift[k]).
template <int KPAD, int CPAD, bool INBF, bool OUTBF>
__global__ __launch_bounds__(256) void k_gemm(const void* __restrict__ in_, int K, int C,
                                              const float* __restrict__ ss,
                                              const unsigned short* __restrict__ WT,
                                              const float* __restrict__ bias,
                                              void* __restrict__ out_, float* __restrict__ stats) {
  constexpr int KL = KPAD + 8;        // LDS row pad
  constexpr int NCT = CPAD / 16;
  __shared__ __attribute__((aligned(16))) unsigned short Alds[64 * KL];
  __shared__ float s_sum[128], s_sq[128], sss[256];
  int tid = threadIdx.x;
  int rowbase = blockIdx.x * 64;
  if (stats && tid < 128) { s_sum[tid] = 0.f; s_sq[tid] = 0.f; }
  if (ss && tid < 256) sss[tid] = ss[tid];
  if (ss) __syncthreads();

  if (INBF) {
    const unsigned short* in = (const unsigned short*)in_;
    for (int idx8 = tid; idx8 < 64 * KPAD / 8; idx8 += 256) {
      int r = idx8 / (KPAD / 8);
      int k = (idx8 - r * (KPAD / 8)) * 8;
      int gr = rowbase + r;
      bh8 v = {};
      if (gr < NN) v = *(const bh8*)(in + (size_t)gr * K + k);
      if (ss) {
#pragma unroll
        for (int i = 0; i < 8; ++i) {
          float f = bf2f((unsigned short)v[i]);
          f = fmaxf(fmaf(f, sss[k + i], sss[128 + k + i]), 0.f);
          v[i] = (short)f2bf(f);
        }
      }
      *(bh8*)&Alds[r * KL + k] = v;
    }
  } else {  // fp32 input, scalar staging with zero-pad (K=165 -> 192), no pre-transform
    const float* in = (const float*)in_;
    for (int idx = tid; idx < 64 * KPAD; idx += 256) {
      int r = idx / KPAD, k = idx - r * KPAD;
      int gr = rowbase + r;
      float v = (gr < NN && k < K) ? in[(size_t)gr * K + k] : 0.f;
      Alds[r * KL + k] = f2bf(v);
    }
  }
  __syncthreads();

  int lane = tid & 63, wave = tid >> 6;
  int lr = lane & 15, lk = (lane >> 4) * 8;
  f4 acc[NCT] = {};
  for (int kt = 0; kt < KPAD / 32; ++kt) {
    bh8 a = *(const bh8*)&Alds[(wave * 16 + lr) * KL + kt * 32 + lk];
#pragma unroll
    for (int ct = 0; ct < NCT; ++ct) {
      bh8 b = *(const bh8*)&WT[(ct * 16 + lr) * KPAD + kt * 32 + lk];
      acc[ct] = __builtin_amdgcn_mfma_f32_16x16x32_bf16(a, b, acc[ct], 0, 0, 0);
    }
  }

  int r0 = rowbase + wave * 16 + (lane >> 4) * 4;
#pragma unroll
  for (int ct = 0; ct < NCT; ++ct) {
    int c = ct * 16 + lr;
    float bv = (bias != nullptr && c < C) ? bias[c] : 0.f;
    float cs = 0.f, cq = 0.f;
#pragma unroll
    for (int rg = 0; rg < 4; ++rg) {
      int gr = r0 + rg;
      if (gr < NN && c < C) {
        float v = acc[ct][rg] + bv;
        if (OUTBF) {
          unsigned short ub = f2bf(v);
          ((unsigned short*)out_)[(size_t)gr * C + c] = ub;
          v = bf2f(ub);  // stats on rounded value (matches consumer)
        } else {
          ((float*)out_)[(size_t)gr * C + c] = v;
        }
        cs += v; cq += v * v;
      }
    }
    if (stats && c < C) { atomicAdd(&s_sum[c], cs); atomicAdd(&s_sq[c], cq); }
  }
  if (stats) {
    __syncthreads();
    int slot = blockIdx.x & 63;
    if (tid < 128) {
      atomicAdd(&stats[slot * 256 + tid], s_sum[tid]);
      atomicAdd(&stats[slot * 256 + 128 + tid], s_sq[tid]);
    }
  }
}

// ---------- GCN aggregation (bf16 table): out[i] = dinv_i^2*t[i] + sum dinv[s]*dinv_i*t[s] ----------
__global__ __launch_bounds__(256) void k_agg(const unsigned short* __restrict__ t, const int* __restrict__ colv,
                                             const int* __restrict__ rowptr, const int* __restrict__ deg,
                                             const float* __restrict__ dinv, unsigned short* __restrict__ out,
                                             float* __restrict__ stats) {
  __shared__ float rs[4][128], rq[4][128];
  int lane = threadIdx.x & 63, wave = threadIdx.x >> 6;
  int node = blockIdx.x * 4 + wave;
  float a0 = 0.f, a1 = 0.f;
  if (node < NN) {
    float di = dinv[node];
    uint32_t sv = *(const uint32_t*)(t + (size_t)node * 128 + lane * 2);
    a0 = di * di * bflo(sv); a1 = di * di * bfhi(sv);
    int start = rowptr[node], len = deg[node];
    for (int j0 = 0; j0 < len; j0 += 64) {
      int cnt = min(len - j0, 64);
      int id = 0; float dv = 0.f;
      if (lane < cnt) { id = colv[start + j0 + lane]; dv = dinv[id]; }
      int j = 0;
      for (; j + 4 <= cnt; j += 4) {  // 4 row-loads in flight
        int s0 = __shfl(id, j),     s1 = __shfl(id, j + 1);
        int s2 = __shfl(id, j + 2), s3 = __shfl(id, j + 3);
        float c0 = __shfl(dv, j) * di,     c1 = __shfl(dv, j + 1) * di;
        float c2 = __shfl(dv, j + 2) * di, c3 = __shfl(dv, j + 3) * di;
        uint32_t v0 = *(const uint32_t*)(t + (size_t)s0 * 128 + lane * 2);
        uint32_t v1 = *(const uint32_t*)(t + (size_t)s1 * 128 + lane * 2);
        uint32_t v2 = *(const uint32_t*)(t + (size_t)s2 * 128 + lane * 2);
        uint32_t v3 = *(const uint32_t*)(t + (size_t)s3 * 128 + lane * 2);
        a0 = fmaf(c0, bflo(v0), a0); a1 = fmaf(c0, bfhi(v0), a1);
        a0 = fmaf(c1, bflo(v1), a0); a1 = fmaf(c1, bfhi(v1), a1);
        a0 = fmaf(c2, bflo(v2), a0); a1 = fmaf(c2, bfhi(v2), a1);
        a0 = fmaf(c3, bflo(v3), a0); a1 = fmaf(c3, bfhi(v3), a1);
      }
      for (; j < cnt; ++j) {
        int s = __shfl(id, j);
        float c = __shfl(dv, j) * di;
        uint32_t v = *(const uint32_t*)(t + (size_t)s * 128 + lane * 2);
        a0 = fmaf(c, bflo(v), a0); a1 = fmaf(c, bfhi(v), a1);
      }
    }
    unsigned short u0 = f2bf(a0), u1 = f2bf(a1);
    *(uint32_t*)(out + (size_t)node * 128 + lane * 2) = (uint32_t)u0 | ((uint32_t)u1 << 16);
    a0 = bf2f(u0); a1 = bf2f(u1);  // stats on rounded values
  }
  rs[wave][lane * 2] = a0; rs[wave][lane * 2 + 1] = a1;
  rq[wave][lane * 2] = a0 * a0; rq[wave][lane * 2 + 1] = a1 * a1;
  __syncthreads();
  if (threadIdx.x < 128) {
    int c = threadIdx.x;
    float s = rs[0][c] + rs[1][c] + rs[2][c] + rs[3][c];
    float q = rq[0][c] + rq[1][c] + rq[2][c] + rq[3][c];
    int slot = blockIdx.x & 63;
    atomicAdd(&stats[slot * 256 + c], s);
    atomicAdd(&stats[slot * 256 + 128 + c], q);
  }
}

// ---------- BN finalize: (sum,sumsq,g,be) -> scale/shift ----------
__global__ __launch_bounds__(128) void k_finalize(const float* __restrict__ stats, const float* __restrict__ g,
                                                  const float* __restrict__ be, float* __restrict__ ssout, int C) {
  int c = threadIdx.x;
  if (c < C) {
    float s = 0.f, q = 0.f;
    for (int k = 0; k < 64; ++k) { s += stats[k * 256 + c]; q += stats[k * 256 + 128 + c]; }
    const float invN = 1.f / (float)NN;
    float mean = s * invN;
    float var = fmaxf(q * invN - mean * mean, 0.f);
    float scale = g[c] * rsqrtf(var + 1e-5f);
    ssout[c] = scale;
    ssout[128 + c] = be[c] - mean * scale;
  }
}

// ---------- emb = relu(bn(a2)): write fp32 to d_out AND bf16 copy for the heads ----------
__global__ __launch_bounds__(256) void k_embwrite(const unsigned short* __restrict__ a2h,
                                                  const float* __restrict__ ss,
                                                  float* __restrict__ emb, unsigned short* __restrict__ embh) {
  int idx = blockIdx.x * 256 + threadIdx.x;  // 4 cols per thread
  if (idx < NN * 32) {
    int cb = (idx & 31) * 4;
    uint2 v = *(const uint2*)(a2h + (size_t)idx * 4);
    float f0 = fmaxf(fmaf(bflo(v.x), ss[cb],     ss[128 + cb]), 0.f);
    float f1 = fmaxf(fmaf(bfhi(v.x), ss[cb + 1], ss[129 + cb]), 0.f);
    float f2 = fmaxf(fmaf(bflo(v.y), ss[cb + 2], ss[130 + cb]), 0.f);
    float f3 = fmaxf(fmaf(bfhi(v.y), ss[cb + 3], ss[131 + cb]), 0.f);
    *(float4*)(emb + (size_t)idx * 4) = make_float4(f0, f1, f2, f3);
    uint2 o;
    o.x = (uint32_t)f2bf(f0) | ((uint32_t)f2bf(f1) << 16);
    o.y = (uint32_t)f2bf(f2) | ((uint32_t)f2bf(f3) << 16);
    *(uint2*)(embh + (size_t)idx * 4) = o;
  }
}

extern "C" void kernel_launch(void* const* d_in, const int* in_sizes, int n_in,
                              void* d_out, int out_size, void* d_ws, size_t ws_size,
                              hipStream_t stream) {
  (void)in_sizes; (void)n_in; (void)out_size; (void)ws_size;
  const float* x   = (const float*)d_in[0];
  const int*   ei  = (const int*)d_in[1];
  const float* W1  = (const float*)d_in[2];
  const float* W2  = (const float*)d_in[4];
  const float* g1  = (const float*)d_in[6];
  const float* be1 = (const float*)d_in[7];
  const float* g2  = (const float*)d_in[8];
  const float* be2 = (const float*)d_in[9];
  const float* fW1 = (const float*)d_in[10];
  const float* fg1 = (const float*)d_in[12];
  const float* fbe1= (const float*)d_in[13];
  const float* fW2 = (const float*)d_in[14];
  const float* fg2 = (const float*)d_in[16];
  const float* fbe2= (const float*)d_in[17];
  const float* fW3 = (const float*)d_in[18];
  const float* fb3 = (const float*)d_in[19];
  const float* bW1 = (const float*)d_in[20];
  const float* bg1 = (const float*)d_in[22];
  const float* bbe1= (const float*)d_in[23];
  const float* bW2 = (const float*)d_in[24];
  const float* bb2 = (const float*)d_in[25];

  float* outp = (float*)d_out;
  float* fl  = outp;                       // [NN,50]
  float* bl  = outp + (size_t)NN * 50;     // [NN,3]
  float* emb = outp + (size_t)NN * 53;     // [NN,128]

  char* wsb = (char*)d_ws;
  int*   deg    = (int*)(wsb + OFF_DEG);
  float* stats  = (float*)(wsb + OFF_STATS);
  int*   rowptr = (int*)(wsb + OFF_ROWPTR);
  int*   fillp  = (int*)(wsb + OFF_FILLP);
  float* dinv   = (float*)(wsb + OFF_DINV);
  int*   blk    = (int*)(wsb + OFF_BLK);
  float* ssb    = (float*)(wsb + OFF_SS);
  const unsigned short* W1T  = (const unsigned short*)(wsb + OFF_W1T);
  const unsigned short* W2T  = (const unsigned short*)(wsb + OFF_W2T);
  const unsigned short* FW1T = (const unsigned short*)(wsb + OFF_FW1T);
  const unsigned short* FW2T = (const unsigned short*)(wsb + OFF_FW2T);
  const unsigned short* FW3T = (const unsigned short*)(wsb + OFF_FW3T);
  const unsigned short* BW1T = (const unsigned short*)(wsb + OFF_BW1T);
  const unsigned short* BW2T = (const unsigned short*)(wsb + OFF_BW2T);
  int*            colv = (int*)(wsb + OFF_COL);
  unsigned short* buf0 = (unsigned short*)(wsb + OFF_BUF0);
  unsigned short* buf1 = (unsigned short*)(wsb + OFF_BUF1);
  unsigned short* buf2 = (unsigned short*)(wsb + OFF_BUF2);

  const int GE = (NE + 255) / 256;     // 6250
  const int GG = (NN + 63) / 64;       // 1563
  const int GA = (NN + 3) / 4;         // 25000

  hipMemsetAsync(d_ws, 0, ZERO_BYTES, stream);  // deg + stats

  // CSR (dst-major) + dinv
  k_hist <<<GE, 256, 0, stream>>>(ei + NE, deg);
  k_scan1<<<NBS, 256, 0, stream>>>(deg, blk);
  k_scan2<<<1, 512, 0, stream>>>(blk);
  k_scan3<<<NBS, 256, 0, stream>>>(deg, blk, rowptr, fillp, dinv);
  k_fill <<<GE, 256, 0, stream>>>(ei, ei + NE, fillp, colv);
  k_wprep<<<308, 256, 0, stream>>>(W1, W2, fW1, fW2, fW3, bW1, bW2, wsb);

  // GCN layer 1: t1 = x@W1 ; a1 = A_hat t1 ; bn1
  k_gemm<192, 128, false, true><<<GG, 256, 0, stream>>>(x, DIN, 128, nullptr, W1T, nullptr, buf0, nullptr);
  k_agg<<<GA, 256, 0, stream>>>(buf0, colv, rowptr, deg, dinv, buf1, stats + 0 * 16384);
  k_finalize<<<1, 128, 0, stream>>>(stats + 0 * 16384, g1, be1, ssb + 0 * 256, 128);

  // GCN layer 2: t2 = relu(bn1(a1))@W2 ; a2 = A_hat t2 ; bn2
  k_gemm<128, 128, true, true><<<GG, 256, 0, stream>>>(buf1, 128, 128, ssb + 0 * 256, W2T, nullptr, buf0, nullptr);
  k_agg<<<GA, 256, 0, stream>>>(buf0, colv, rowptr, deg, dinv, buf1, stats + 1 * 16384);
  k_finalize<<<1, 128, 0, stream>>>(stats + 1 * 16384, g2, be2, ssb + 1 * 256, 128);

  // emb = relu(bn2(a2)) -> d_out fp32 + bf16 copy
  k_embwrite<<<NN * 32 / 256, 256, 0, stream>>>(buf1, ssb + 1 * 256, emb, buf2);

  // forward head
  k_gemm<128, 128, true, true><<<GG, 256, 0, stream>>>(buf2, 128, 128, nullptr, FW1T, nullptr, buf0, stats + 2 * 16384);
  k_finalize<<<1, 128, 0, stream>>>(stats + 2 * 16384, fg1, fbe1, ssb + 2 * 256, 128);
  k_gemm<128, 64, true, true><<<GG, 256, 0, stream>>>(buf0, 128, 64, ssb + 2 * 256, FW2T, nullptr, buf1, stats + 3 * 16384);
  k_finalize<<<1, 128, 0, stream>>>(stats + 3 * 16384, fg2, fbe2, ssb + 3 * 256, 64);
  k_gemm<64, 64, true, false><<<GG, 256, 0, stream>>>(buf1, 64, 50, ssb + 3 * 256, FW3T, fb3, fl, nullptr);

  // backward head
  k_gemm<128, 64, true, true><<<GG, 256, 0, stream>>>(buf2, 128, 64, nullptr, BW1T, nullptr, buf0, stats + 4 * 16384);
  k_finalize<<<1, 128, 0, stream>>>(stats + 4 * 16384, bg1, bbe1, ssb + 4 * 256, 64);
  k_gemm<64, 16, true, false><<<GG, 256, 0, stream>>>(buf0, 64, 3, ssb + 4 * 256, BW2T, bb2, bl, nullptr);
}

// Round 3
// 612.212 us; speedup vs baseline: 1.3767x; 1.1107x over previous
//
#include <hip/hip_runtime.h>
#include <stdint.h>

// ---------- problem constants ----------
constexpr int NN = 100000;   // nodes
constexpr int NE = 1600000;  // edges
constexpr int DIN = 165;     // input feat
constexpr int PSZ = 12500;   // NN / 8 dst-partition size (XCD locality)

typedef __attribute__((ext_vector_type(8))) short bh8;   // 8 x bf16 bits
typedef __attribute__((ext_vector_type(4))) float f4;    // mfma acc

__device__ inline unsigned short f2bf(float x) {
  union { float f; uint32_t u; } un; un.f = x;
  uint32_t u = un.u;
  return (unsigned short)((u + 0x7FFFu + ((u >> 16) & 1u)) >> 16);  // RNE
}
__device__ inline float bf2f(unsigned short u) {
  union { uint32_t i; float f; } c; c.i = (uint32_t)u << 16; return c.f;
}
__device__ inline float bflo(uint32_t v) {
  union { uint32_t i; float f; } c; c.i = v << 16; return c.f;
}
__device__ inline float bfhi(uint32_t v) {
  union { uint32_t i; float f; } c; c.i = v & 0xffff0000u; return c.f;
}

// ---------- workspace byte offsets ----------
constexpr size_t OFF_DEG    = 0;                          // int[NN]            (zeroed)
constexpr size_t OFF_STATS  = 400128;                     // float[5*64*256]    (zeroed)
constexpr size_t ZERO_BYTES = OFF_STATS + (size_t)5*64*256*4;   // 727808
constexpr size_t OFF_ROWPTR = ZERO_BYTES;                 // int[NN]
constexpr size_t OFF_FILLP  = OFF_ROWPTR + 400128;
constexpr size_t OFF_DINV   = OFF_FILLP + 400128;         // float[NN]
constexpr size_t OFF_BLK    = OFF_DINV + 400128;          // int[512]
constexpr size_t OFF_SS     = OFF_BLK + 2048;             // float[5*256] scale/shift
constexpr size_t OFF_W1T    = OFF_SS + 5*256*4;           // bf16 [128][192]
constexpr size_t OFF_W2T    = OFF_W1T + 128*192*2;        // bf16 [128][128]
constexpr size_t OFF_FW1T   = OFF_W2T + 128*128*2;        // bf16 [128][128]
constexpr size_t OFF_FW2T   = OFF_FW1T + 128*128*2;       // bf16 [64][128]
constexpr size_t OFF_FW3T   = OFF_FW2T + 64*128*2;        // bf16 [64][64]
constexpr size_t OFF_BW1T   = OFF_FW3T + 64*64*2;         // bf16 [64][128]
constexpr size_t OFF_BW2T   = OFF_BW1T + 64*128*2;        // bf16 [16][64]
constexpr size_t OFF_COL    = (OFF_BW2T + 16*64*2 + 255) & ~(size_t)255;      // int[NE]
constexpr size_t OFF_BUF0   = (OFF_COL + (size_t)NE*4 + 255) & ~(size_t)255;  // bf16[NN*128]
constexpr size_t OFF_BUF1   = OFF_BUF0 + (size_t)NN*128*2;                    // bf16[NN*128]
constexpr size_t OFF_BUF2   = OFF_BUF1 + (size_t)NN*128*2;                    // bf16[NN*128]

constexpr int NBS = (NN + 255) / 256;  // 391 scan blocks

// ---------- CSR build (dst-partitioned for L2 locality) ----------
// Each block owns dst-partition (blockIdx&7) ~ one XCD under round-robin dispatch;
// it streams the (L3-resident) edge list and only touches a 50KB fillptr slice +
// 0.8MB colv slice -> atomics and scatter stay cache-resident.
__global__ __launch_bounds__(256) void k_hist(const int* __restrict__ dst, int* __restrict__ deg) {
  int part = blockIdx.x & 7;
  int lo = part * PSZ, hi = lo + PSZ;
  int stride = (gridDim.x >> 3) * 256;
  for (int e = (blockIdx.x >> 3) * 256 + threadIdx.x; e < NE; e += stride) {
    int d = dst[e];
    if (d >= lo && d < hi) atomicAdd(&deg[d], 1);
  }
}

__global__ __launch_bounds__(256) void k_fill(const int* __restrict__ srcv, const int* __restrict__ dstv,
                                              int* __restrict__ fillptr, int* __restrict__ colv) {
  int part = blockIdx.x & 7;
  int lo = part * PSZ, hi = lo + PSZ;
  int stride = (gridDim.x >> 3) * 256;
  for (int e = (blockIdx.x >> 3) * 256 + threadIdx.x; e < NE; e += stride) {
    int d = dstv[e];
    if (d >= lo && d < hi) {
      int p = atomicAdd(&fillptr[d], 1);
      colv[p] = srcv[e];
    }
  }
}

__global__ __launch_bounds__(256) void k_scan1(const int* __restrict__ deg, int* __restrict__ bsum) {
  __shared__ int sh[256];
  int i = blockIdx.x * 256 + threadIdx.x;
  sh[threadIdx.x] = (i < NN) ? deg[i] : 0;
  __syncthreads();
  for (int o = 128; o > 0; o >>= 1) {
    if (threadIdx.x < o) sh[threadIdx.x] += sh[threadIdx.x + o];
    __syncthreads();
  }
  if (threadIdx.x == 0) bsum[blockIdx.x] = sh[0];
}

__global__ __launch_bounds__(512) void k_scan2(int* __restrict__ bsum) {
  __shared__ int sh[512];
  int t = threadIdx.x;
  int v = (t < NBS) ? bsum[t] : 0;
  sh[t] = v; __syncthreads();
  for (int o = 1; o < 512; o <<= 1) {
    int x = (t >= o) ? sh[t - o] : 0;
    __syncthreads();
    sh[t] += x;
    __syncthreads();
  }
  if (t < NBS) bsum[t] = sh[t] - v;  // exclusive block offsets
}

__global__ __launch_bounds__(256) void k_scan3(const int* __restrict__ deg, const int* __restrict__ boff,
                                               int* __restrict__ rowptr, int* __restrict__ fillptr,
                                               float* __restrict__ dinv) {
  __shared__ int sh[256];
  int t = threadIdx.x, i = blockIdx.x * 256 + t;
  int v = (i < NN) ? deg[i] : 0;
  sh[t] = v; __syncthreads();
  for (int o = 1; o < 256; o <<= 1) {
    int x = (t >= o) ? sh[t - o] : 0;
    __syncthreads();
    sh[t] += x;
    __syncthreads();
  }
  if (i < NN) {
    int excl = sh[t] - v + boff[blockIdx.x];
    rowptr[i] = excl; fillptr[i] = excl;
    dinv[i] = rsqrtf((float)(v + 1));  // +1 self-loop
  }
}

// ---------- weight prep: W[K,C] fp32 -> WT[Cpad][Kpad] bf16 ----------
__global__ __launch_bounds__(256) void k_wprep(const float* __restrict__ W1, const float* __restrict__ W2,
                                               const float* __restrict__ fW1, const float* __restrict__ fW2,
                                               const float* __restrict__ fW3, const float* __restrict__ bW1,
                                               const float* __restrict__ bW2, char* __restrict__ wsb) {
  int b = blockIdx.x, t = threadIdx.x;
  const float* src; unsigned short* dst; int K, C, Kpad, base;
  if (b < 96)       { src = W1;  dst = (unsigned short*)(wsb + OFF_W1T);  K = DIN; C = 128; Kpad = 192; base = b; }
  else if (b < 160) { src = W2;  dst = (unsigned short*)(wsb + OFF_W2T);  K = 128; C = 128; Kpad = 128; base = b - 96; }
  else if (b < 224) { src = fW1; dst = (unsigned short*)(wsb + OFF_FW1T); K = 128; C = 128; Kpad = 128; base = b - 160; }
  else if (b < 256) { src = fW2; dst = (unsigned short*)(wsb + OFF_FW2T); K = 128; C = 64;  Kpad = 128; base = b - 224; }
  else if (b < 272) { src = fW3; dst = (unsigned short*)(wsb + OFF_FW3T); K = 64;  C = 50;  Kpad = 64;  base = b - 256; }
  else if (b < 304) { src = bW1; dst = (unsigned short*)(wsb + OFF_BW1T); K = 128; C = 64;  Kpad = 128; base = b - 272; }
  else              { src = bW2; dst = (unsigned short*)(wsb + OFF_BW2T); K = 64;  C = 3;   Kpad = 64;  base = b - 304; }
  int idx = base * 256 + t;
  int c = idx / Kpad, k = idx - c * Kpad;
  float v = (c < C && k < K) ? src[k * C + c] : 0.f;
  dst[idx] = f2bf(v);
}

// ---------- fused GEMM: out[N,C] = pre(in[N,K]) @ W[K,C] (+bias) (+BN stats) ----------
// pre = identity (ss==null) or relu(in*scale[k]+shift[k]).
template <int KPAD, int CPAD, bool INBF, bool OUTBF>
__global__ __launch_bounds__(256) void k_gemm(const void* __restrict__ in_, int K, int C,
                                              const float* __restrict__ ss,
                                              const unsigned short* __restrict__ WT,
                                              const float* __restrict__ bias,
                                              void* __restrict__ out_, float* __restrict__ stats) {
  constexpr int KL = KPAD + 8;        // LDS row pad
  constexpr int NCT = CPAD / 16;
  __shared__ __attribute__((aligned(16))) unsigned short Alds[64 * KL];
  __shared__ float s_sum[128], s_sq[128], sss[256];
  int tid = threadIdx.x;
  int rowbase = blockIdx.x * 64;
  if (stats && tid < 128) { s_sum[tid] = 0.f; s_sq[tid] = 0.f; }
  if (ss && tid < 256) sss[tid] = ss[tid];
  if (ss) __syncthreads();

  if (INBF) {
    const unsigned short* in = (const unsigned short*)in_;
    for (int idx8 = tid; idx8 < 64 * KPAD / 8; idx8 += 256) {
      int r = idx8 / (KPAD / 8);
      int k = (idx8 - r * (KPAD / 8)) * 8;
      int gr = rowbase + r;
      bh8 v = {};
      if (gr < NN) v = *(const bh8*)(in + (size_t)gr * K + k);
      if (ss) {
#pragma unroll
        for (int i = 0; i < 8; ++i) {
          float f = bf2f((unsigned short)v[i]);
          f = fmaxf(fmaf(f, sss[k + i], sss[128 + k + i]), 0.f);
          v[i] = (short)f2bf(f);
        }
      }
      *(bh8*)&Alds[r * KL + k] = v;
    }
  } else {  // fp32 input, scalar staging with zero-pad (K=165 -> 192)
    const float* in = (const float*)in_;
    for (int idx = tid; idx < 64 * KPAD; idx += 256) {
      int r = idx / KPAD, k = idx - r * KPAD;
      int gr = rowbase + r;
      float v = (gr < NN && k < K) ? in[(size_t)gr * K + k] : 0.f;
      Alds[r * KL + k] = f2bf(v);
    }
  }
  __syncthreads();

  int lane = tid & 63, wave = tid >> 6;
  int lr = lane & 15, lk = (lane >> 4) * 8;
  f4 acc[NCT] = {};
  for (int kt = 0; kt < KPAD / 32; ++kt) {
    bh8 a = *(const bh8*)&Alds[(wave * 16 + lr) * KL + kt * 32 + lk];
#pragma unroll
    for (int ct = 0; ct < NCT; ++ct) {
      bh8 b = *(const bh8*)&WT[(ct * 16 + lr) * KPAD + kt * 32 + lk];
      acc[ct] = __builtin_amdgcn_mfma_f32_16x16x32_bf16(a, b, acc[ct], 0, 0, 0);
    }
  }

  int r0 = rowbase + wave * 16 + (lane >> 4) * 4;
#pragma unroll
  for (int ct = 0; ct < NCT; ++ct) {
    int c = ct * 16 + lr;
    float bv = (bias != nullptr && c < C) ? bias[c] : 0.f;
    float cs = 0.f, cq = 0.f;
#pragma unroll
    for (int rg = 0; rg < 4; ++rg) {
      int gr = r0 + rg;
      if (gr < NN && c < C) {
        float v = acc[ct][rg] + bv;
        if (OUTBF) {
          unsigned short ub = f2bf(v);
          ((unsigned short*)out_)[(size_t)gr * C + c] = ub;
          v = bf2f(ub);  // stats on rounded value (matches consumer)
        } else {
          ((float*)out_)[(size_t)gr * C + c] = v;
        }
        cs += v; cq += v * v;
      }
    }
    if (stats && c < C) { atomicAdd(&s_sum[c], cs); atomicAdd(&s_sq[c], cq); }
  }
  if (stats) {
    __syncthreads();
    int slot = blockIdx.x & 63;
    if (tid < 128) {
      atomicAdd(&stats[slot * 256 + tid], s_sum[tid]);
      atomicAdd(&stats[slot * 256 + 128 + tid], s_sq[tid]);
    }
  }
}

// ---------- GCN aggregation (bf16 table) ----------
__global__ __launch_bounds__(256) void k_agg(const unsigned short* __restrict__ t, const int* __restrict__ colv,
                                             const int* __restrict__ rowptr, const int* __restrict__ deg,
                                             const float* __restrict__ dinv, unsigned short* __restrict__ out,
                                             float* __restrict__ stats) {
  __shared__ float rs[4][128], rq[4][128];
  int lane = threadIdx.x & 63, wave = threadIdx.x >> 6;
  int node = blockIdx.x * 4 + wave;
  float a0 = 0.f, a1 = 0.f;
  if (node < NN) {
    float di = dinv[node];
    uint32_t sv = *(const uint32_t*)(t + (size_t)node * 128 + lane * 2);
    a0 = di * di * bflo(sv); a1 = di * di * bfhi(sv);
    int start = rowptr[node], len = deg[node];
    for (int j0 = 0; j0 < len; j0 += 64) {
      int cnt = min(len - j0, 64);
      int id = 0; float dv = 0.f;
      if (lane < cnt) { id = colv[start + j0 + lane]; dv = dinv[id]; }
      int j = 0;
      for (; j + 4 <= cnt; j += 4) {  // 4 row-loads in flight
        int s0 = __shfl(id, j),     s1 = __shfl(id, j + 1);
        int s2 = __shfl(id, j + 2), s3 = __shfl(id, j + 3);
        float c0 = __shfl(dv, j) * di,     c1 = __shfl(dv, j + 1) * di;
        float c2 = __shfl(dv, j + 2) * di, c3 = __shfl(dv, j + 3) * di;
        uint32_t v0 = *(const uint32_t*)(t + (size_t)s0 * 128 + lane * 2);
        uint32_t v1 = *(const uint32_t*)(t + (size_t)s1 * 128 + lane * 2);
        uint32_t v2 = *(const uint32_t*)(t + (size_t)s2 * 128 + lane * 2);
        uint32_t v3 = *(const uint32_t*)(t + (size_t)s3 * 128 + lane * 2);
        a0 = fmaf(c0, bflo(v0), a0); a1 = fmaf(c0, bfhi(v0), a1);
        a0 = fmaf(c1, bflo(v1), a0); a1 = fmaf(c1, bfhi(v1), a1);
        a0 = fmaf(c2, bflo(v2), a0); a1 = fmaf(c2, bfhi(v2), a1);
        a0 = fmaf(c3, bflo(v3), a0); a1 = fmaf(c3, bfhi(v3), a1);
      }
      for (; j < cnt; ++j) {
        int s = __shfl(id, j);
        float c = __shfl(dv, j) * di;
        uint32_t v = *(const uint32_t*)(t + (size_t)s * 128 + lane * 2);
        a0 = fmaf(c, bflo(v), a0); a1 = fmaf(c, bfhi(v), a1);
      }
    }
    unsigned short u0 = f2bf(a0), u1 = f2bf(a1);
    *(uint32_t*)(out + (size_t)node * 128 + lane * 2) = (uint32_t)u0 | ((uint32_t)u1 << 16);
    a0 = bf2f(u0); a1 = bf2f(u1);  // stats on rounded values
  }
  rs[wave][lane * 2] = a0; rs[wave][lane * 2 + 1] = a1;
  rq[wave][lane * 2] = a0 * a0; rq[wave][lane * 2 + 1] = a1 * a1;
  __syncthreads();
  if (threadIdx.x < 128) {
    int c = threadIdx.x;
    float s = rs[0][c] + rs[1][c] + rs[2][c] + rs[3][c];
    float q = rq[0][c] + rq[1][c] + rq[2][c] + rq[3][c];
    int slot = blockIdx.x & 63;
    atomicAdd(&stats[slot * 256 + c], s);
    atomicAdd(&stats[slot * 256 + 128 + c], q);
  }
}

// ---------- BN finalize ----------
__global__ __launch_bounds__(128) void k_finalize(const float* __restrict__ stats, const float* __restrict__ g,
                                                  const float* __restrict__ be, float* __restrict__ ssout, int C) {
  int c = threadIdx.x;
  if (c < C) {
    float s = 0.f, q = 0.f;
    for (int k = 0; k < 64; ++k) { s += stats[k * 256 + c]; q += stats[k * 256 + 128 + c]; }
    const float invN = 1.f / (float)NN;
    float mean = s * invN;
    float var = fmaxf(q * invN - mean * mean, 0.f);
    float scale = g[c] * rsqrtf(var + 1e-5f);
    ssout[c] = scale;
    ssout[128 + c] = be[c] - mean * scale;
  }
}

// ---------- emb = relu(bn(a2)): fp32 to d_out AND bf16 copy for heads ----------
__global__ __launch_bounds__(256) void k_embwrite(const unsigned short* __restrict__ a2h,
                                                  const float* __restrict__ ss,
                                                  float* __restrict__ emb, unsigned short* __restrict__ embh) {
  int idx = blockIdx.x * 256 + threadIdx.x;  // 4 cols per thread
  if (idx < NN * 32) {
    int cb = (idx & 31) * 4;
    uint2 v = *(const uint2*)(a2h + (size_t)idx * 4);
    float f0 = fmaxf(fmaf(bflo(v.x), ss[cb],     ss[128 + cb]), 0.f);
    float f1 = fmaxf(fmaf(bfhi(v.x), ss[cb + 1], ss[129 + cb]), 0.f);
    float f2 = fmaxf(fmaf(bflo(v.y), ss[cb + 2], ss[130 + cb]), 0.f);
    float f3 = fmaxf(fmaf(bfhi(v.y), ss[cb + 3], ss[131 + cb]), 0.f);
    *(float4*)(emb + (size_t)idx * 4) = make_float4(f0, f1, f2, f3);
    uint2 o;
    o.x = (uint32_t)f2bf(f0) | ((uint32_t)f2bf(f1) << 16);
    o.y = (uint32_t)f2bf(f2) | ((uint32_t)f2bf(f3) << 16);
    *(uint2*)(embh + (size_t)idx * 4) = o;
  }
}

extern "C" void kernel_launch(void* const* d_in, const int* in_sizes, int n_in,
                              void* d_out, int out_size, void* d_ws, size_t ws_size,
                              hipStream_t stream) {
  (void)in_sizes; (void)n_in; (void)out_size; (void)ws_size;
  const float* x   = (const float*)d_in[0];
  const int*   ei  = (const int*)d_in[1];
  const float* W1  = (const float*)d_in[2];
  const float* W2  = (const float*)d_in[4];
  const float* g1  = (const float*)d_in[6];
  const float* be1 = (const float*)d_in[7];
  const float* g2  = (const float*)d_in[8];
  const float* be2 = (const float*)d_in[9];
  const float* fW1 = (const float*)d_in[10];
  const float* fg1 = (const float*)d_in[12];
  const float* fbe1= (const float*)d_in[13];
  const float* fW2 = (const float*)d_in[14];
  const float* fg2 = (const float*)d_in[16];
  const float* fbe2= (const float*)d_in[17];
  const float* fW3 = (const float*)d_in[18];
  const float* fb3 = (const float*)d_in[19];
  const float* bW1 = (const float*)d_in[20];
  const float* bg1 = (const float*)d_in[22];
  const float* bbe1= (const float*)d_in[23];
  const float* bW2 = (const float*)d_in[24];
  const float* bb2 = (const float*)d_in[25];

  float* outp = (float*)d_out;
  float* fl  = outp;                       // [NN,50]
  float* bl  = outp + (size_t)NN * 50;     // [NN,3]
  float* emb = outp + (size_t)NN * 53;     // [NN,128]

  char* wsb = (char*)d_ws;
  int*   deg    = (int*)(wsb + OFF_DEG);
  float* stats  = (float*)(wsb + OFF_STATS);
  int*   rowptr = (int*)(wsb + OFF_ROWPTR);
  int*   fillp  = (int*)(wsb + OFF_FILLP);
  float* dinv   = (float*)(wsb + OFF_DINV);
  int*   blk    = (int*)(wsb + OFF_BLK);
  float* ssb    = (float*)(wsb + OFF_SS);
  const unsigned short* W1T  = (const unsigned short*)(wsb + OFF_W1T);
  const unsigned short* W2T  = (const unsigned short*)(wsb + OFF_W2T);
  const unsigned short* FW1T = (const unsigned short*)(wsb + OFF_FW1T);
  const unsigned short* FW2T = (const unsigned short*)(wsb + OFF_FW2T);
  const unsigned short* FW3T = (const unsigned short*)(wsb + OFF_FW3T);
  const unsigned short* BW1T = (const unsigned short*)(wsb + OFF_BW1T);
  const unsigned short* BW2T = (const unsigned short*)(wsb + OFF_BW2T);
  int*            colv = (int*)(wsb + OFF_COL);
  unsigned short* buf0 = (unsigned short*)(wsb + OFF_BUF0);
  unsigned short* buf1 = (unsigned short*)(wsb + OFF_BUF1);
  unsigned short* buf2 = (unsigned short*)(wsb + OFF_BUF2);

  const int GG = (NN + 63) / 64;       // 1563
  const int GA = (NN + 3) / 4;         // 25000
  const int GP = 1024;                 // partitioned CSR kernels: 128 blocks/partition

  hipMemsetAsync(d_ws, 0, ZERO_BYTES, stream);  // deg + stats

  // CSR (dst-major, dst-partitioned) + dinv
  k_hist <<<GP, 256, 0, stream>>>(ei + NE, deg);
  k_scan1<<<NBS, 256, 0, stream>>>(deg, blk);
  k_scan2<<<1, 512, 0, stream>>>(blk);
  k_scan3<<<NBS, 256, 0, stream>>>(deg, blk, rowptr, fillp, dinv);
  k_fill <<<GP, 256, 0, stream>>>(ei, ei + NE, fillp, colv);
  k_wprep<<<308, 256, 0, stream>>>(W1, W2, fW1, fW2, fW3, bW1, bW2, wsb);

  // GCN layer 1: t1 = x@W1 ; a1 = A_hat t1 ; bn1
  k_gemm<192, 128, false, true><<<GG, 256, 0, stream>>>(x, DIN, 128, nullptr, W1T, nullptr, buf0, nullptr);
  k_agg<<<GA, 256, 0, stream>>>(buf0, colv, rowptr, deg, dinv, buf1, stats + 0 * 16384);
  k_finalize<<<1, 128, 0, stream>>>(stats + 0 * 16384, g1, be1, ssb + 0 * 256, 128);

  // GCN layer 2: t2 = relu(bn1(a1))@W2 ; a2 = A_hat t2 ; bn2
  k_gemm<128, 128, true, true><<<GG, 256, 0, stream>>>(buf1, 128, 128, ssb + 0 * 256, W2T, nullptr, buf0, nullptr);
  k_agg<<<GA, 256, 0, stream>>>(buf0, colv, rowptr, deg, dinv, buf1, stats + 1 * 16384);
  k_finalize<<<1, 128, 0, stream>>>(stats + 1 * 16384, g2, be2, ssb + 1 * 256, 128);

  // emb = relu(bn2(a2)) -> d_out fp32 + bf16 copy
  k_embwrite<<<NN * 32 / 256, 256, 0, stream>>>(buf1, ssb + 1 * 256, emb, buf2);

  // forward head
  k_gemm<128, 128, true, true><<<GG, 256, 0, stream>>>(buf2, 128, 128, nullptr, FW1T, nullptr, buf0, stats + 2 * 16384);
  k_finalize<<<1, 128, 0, stream>>>(stats + 2 * 16384, fg1, fbe1, ssb + 2 * 256, 128);
  k_gemm<128, 64, true, true><<<GG, 256, 0, stream>>>(buf0, 128, 64, ssb + 2 * 256, FW2T, nullptr, buf1, stats + 3 * 16384);
  k_finalize<<<1, 128, 0, stream>>>(stats + 3 * 16384, fg2, fbe2, ssb + 3 * 256, 64);
  k_gemm<64, 64, true, false><<<GG, 256, 0, stream>>>(buf1, 64, 50, ssb + 3 * 256, FW3T, fb3, fl, nullptr);

  // backward head
  k_gemm<128, 64, true, true><<<GG, 256, 0, stream>>>(buf2, 128, 64, nullptr, BW1T, nullptr, buf0, stats + 4 * 16384);
  k_finalize<<<1, 128, 0, stream>>>(stats + 4 * 16384, bg1, bbe1, ssb + 4 * 256, 64);
  k_gemm<64, 16, true, false><<<GG, 256, 0, stream>>>(buf0, 64, 3, ssb + 4 * 256, BW2T, bb2, bl, nullptr);
}

// Round 4
// 589.079 us; speedup vs baseline: 1.4308x; 1.0393x over previous
//
#include <hip/hip_runtime.h>
#include <stdint.h>

// ---------- problem constants ----------
constexpr int NN = 100000;   // nodes
constexpr int NE = 1600000;  // edges
constexpr int DIN = 165;     // input feat
constexpr int PSZ = 12500;   // NN / 8 dst-partition size (XCD locality)

typedef __attribute__((ext_vector_type(8))) short bh8;   // 8 x bf16 bits
typedef __attribute__((ext_vector_type(4))) float f4;    // mfma acc

__device__ inline unsigned short f2bf(float x) {
  union { float f; uint32_t u; } un; un.f = x;
  uint32_t u = un.u;
  return (unsigned short)((u + 0x7FFFu + ((u >> 16) & 1u)) >> 16);  // RNE
}
__device__ inline float bf2f(unsigned short u) {
  union { uint32_t i; float f; } c; c.i = (uint32_t)u << 16; return c.f;
}
__device__ inline float bflo(uint32_t v) {
  union { uint32_t i; float f; } c; c.i = v << 16; return c.f;
}
__device__ inline float bfhi(uint32_t v) {
  union { uint32_t i; float f; } c; c.i = v & 0xffff0000u; return c.f;
}

// ---------- workspace byte offsets ----------
constexpr size_t OFF_DEG    = 0;                          // int[NN]            (zeroed)
constexpr size_t OFF_STATS  = 400128;                     // float[5*64*256]    (zeroed)
constexpr size_t ZERO_BYTES = OFF_STATS + (size_t)5*64*256*4;   // 727808
constexpr size_t OFF_ROWPTR = ZERO_BYTES;                 // int[NN]
constexpr size_t OFF_FILLP  = OFF_ROWPTR + 400128;
constexpr size_t OFF_DINV   = OFF_FILLP + 400128;         // float[NN]
constexpr size_t OFF_BLK    = OFF_DINV + 400128;          // int[512]
constexpr size_t OFF_SS     = OFF_BLK + 2048;             // float[5*256] scale/shift
constexpr size_t OFF_W1T    = OFF_SS + 5*256*4;           // bf16 [128][192]
constexpr size_t OFF_W2T    = OFF_W1T + 128*192*2;        // bf16 [128][128]
constexpr size_t OFF_FW1T   = OFF_W2T + 128*128*2;        // bf16 [128][128]
constexpr size_t OFF_FW2T   = OFF_FW1T + 128*128*2;       // bf16 [64][128]
constexpr size_t OFF_FW3T   = OFF_FW2T + 64*128*2;        // bf16 [64][64]
constexpr size_t OFF_BW1T   = OFF_FW3T + 64*64*2;         // bf16 [64][128]
constexpr size_t OFF_BW2T   = OFF_BW1T + 64*128*2;        // bf16 [16][64]
constexpr size_t OFF_COL    = (OFF_BW2T + 16*64*2 + 255) & ~(size_t)255;      // int[NE]
constexpr size_t OFF_BUF0   = (OFF_COL + (size_t)NE*4 + 255) & ~(size_t)255;  // bf16[NN*128]
constexpr size_t OFF_BUF1   = OFF_BUF0 + (size_t)NN*128*2;                    // bf16[NN*128]
constexpr size_t OFF_BUF2   = OFF_BUF1 + (size_t)NN*128*2;                    // bf16[NN*128]

constexpr int NBS = (NN + 255) / 256;  // 391 scan blocks

// ---------- CSR build (dst-partitioned for L2 locality) ----------
__global__ __launch_bounds__(256) void k_hist(const int* __restrict__ dst, int* __restrict__ deg) {
  int part = blockIdx.x & 7;
  int lo = part * PSZ, hi = lo + PSZ;
  int stride = (gridDim.x >> 3) * 256;
  for (int e = (blockIdx.x >> 3) * 256 + threadIdx.x; e < NE; e += stride) {
    int d = dst[e];
    if (d >= lo && d < hi) atomicAdd(&deg[d], 1);
  }
}

__global__ __launch_bounds__(256) void k_fill(const int* __restrict__ srcv, const int* __restrict__ dstv,
                                              int* __restrict__ fillptr, int* __restrict__ colv) {
  int part = blockIdx.x & 7;
  int lo = part * PSZ, hi = lo + PSZ;
  int stride = (gridDim.x >> 3) * 256;
  for (int e = (blockIdx.x >> 3) * 256 + threadIdx.x; e < NE; e += stride) {
    int d = dstv[e];
    if (d >= lo && d < hi) {
      int p = atomicAdd(&fillptr[d], 1);
      colv[p] = srcv[e];
    }
  }
}

__global__ __launch_bounds__(256) void k_scan1(const int* __restrict__ deg, int* __restrict__ bsum) {
  __shared__ int sh[256];
  int i = blockIdx.x * 256 + threadIdx.x;
  sh[threadIdx.x] = (i < NN) ? deg[i] : 0;
  __syncthreads();
  for (int o = 128; o > 0; o >>= 1) {
    if (threadIdx.x < o) sh[threadIdx.x] += sh[threadIdx.x + o];
    __syncthreads();
  }
  if (threadIdx.x == 0) bsum[blockIdx.x] = sh[0];
}

__global__ __launch_bounds__(512) void k_scan2(int* __restrict__ bsum) {
  __shared__ int sh[512];
  int t = threadIdx.x;
  int v = (t < NBS) ? bsum[t] : 0;
  sh[t] = v; __syncthreads();
  for (int o = 1; o < 512; o <<= 1) {
    int x = (t >= o) ? sh[t - o] : 0;
    __syncthreads();
    sh[t] += x;
    __syncthreads();
  }
  if (t < NBS) bsum[t] = sh[t] - v;  // exclusive block offsets
}

__global__ __launch_bounds__(256) void k_scan3(const int* __restrict__ deg, const int* __restrict__ boff,
                                               int* __restrict__ rowptr, int* __restrict__ fillptr,
                                               float* __restrict__ dinv) {
  __shared__ int sh[256];
  int t = threadIdx.x, i = blockIdx.x * 256 + t;
  int v = (i < NN) ? deg[i] : 0;
  sh[t] = v; __syncthreads();
  for (int o = 1; o < 256; o <<= 1) {
    int x = (t >= o) ? sh[t - o] : 0;
    __syncthreads();
    sh[t] += x;
    __syncthreads();
  }
  if (i < NN) {
    int excl = sh[t] - v + boff[blockIdx.x];
    rowptr[i] = excl; fillptr[i] = excl;
    dinv[i] = rsqrtf((float)(v + 1));  // +1 self-loop
  }
}

// ---------- weight prep: W[K,C] fp32 -> WT[Cpad][Kpad] bf16 ----------
__global__ __launch_bounds__(256) void k_wprep(const float* __restrict__ W1, const float* __restrict__ W2,
                                               const float* __restrict__ fW1, const float* __restrict__ fW2,
                                               const float* __restrict__ fW3, const float* __restrict__ bW1,
                                               const float* __restrict__ bW2, char* __restrict__ wsb) {
  int b = blockIdx.x, t = threadIdx.x;
  const float* src; unsigned short* dst; int K, C, Kpad, base;
  if (b < 96)       { src = W1;  dst = (unsigned short*)(wsb + OFF_W1T);  K = DIN; C = 128; Kpad = 192; base = b; }
  else if (b < 160) { src = W2;  dst = (unsigned short*)(wsb + OFF_W2T);  K = 128; C = 128; Kpad = 128; base = b - 96; }
  else if (b < 224) { src = fW1; dst = (unsigned short*)(wsb + OFF_FW1T); K = 128; C = 128; Kpad = 128; base = b - 160; }
  else if (b < 256) { src = fW2; dst = (unsigned short*)(wsb + OFF_FW2T); K = 128; C = 64;  Kpad = 128; base = b - 224; }
  else if (b < 272) { src = fW3; dst = (unsigned short*)(wsb + OFF_FW3T); K = 64;  C = 50;  Kpad = 64;  base = b - 256; }
  else if (b < 304) { src = bW1; dst = (unsigned short*)(wsb + OFF_BW1T); K = 128; C = 64;  Kpad = 128; base = b - 272; }
  else              { src = bW2; dst = (unsigned short*)(wsb + OFF_BW2T); K = 64;  C = 3;   Kpad = 64;  base = b - 304; }
  int idx = base * 256 + t;
  int c = idx / Kpad, k = idx - c * Kpad;
  float v = (c < C && k < K) ? src[k * C + c] : 0.f;
  dst[idx] = f2bf(v);
}

// ---------- fused GEMM: out[N,C] = pre(in[N,K]) @ W[K,C] (+bias) (+BN stats) ----------
// pre = identity (ss==null) or relu(in*scale[k]+shift[k]).
// INBF=false: fp32 input, K==DIN, KPAD==192; slab of 64 rows = 10560 consecutive
//   16B-aligned floats -> 11 unrolled float4 loads/thread (one latency exposure).
// INBF=true:  bf16 input with stride == KPAD; unrolled bh8 loads to regs.
template <int KPAD, int CPAD, bool INBF, bool OUTBF>
__global__ __launch_bounds__(256) void k_gemm(const void* __restrict__ in_, int K, int C,
                                              const float* __restrict__ ss,
                                              const unsigned short* __restrict__ WT,
                                              const float* __restrict__ bias,
                                              void* __restrict__ out_, float* __restrict__ stats) {
  constexpr int KL = KPAD + 8;        // LDS row pad
  constexpr int NCT = CPAD / 16;
  __shared__ __attribute__((aligned(16))) unsigned short Alds[64 * KL];
  __shared__ float s_sum[128], s_sq[128], sss[256];
  int tid = threadIdx.x;
  int rowbase = blockIdx.x * 64;
  if (stats && tid < 128) { s_sum[tid] = 0.f; s_sq[tid] = 0.f; }
  if (ss && tid < 256) sss[tid] = ss[tid];
  if (ss) __syncthreads();

  if constexpr (INBF) {
    const unsigned short* in = (const unsigned short*)in_;
    constexpr int NL = (64 * KPAD / 8) / 256;   // 2 (KPAD=64), 4 (128)
    bh8 vv[NL];
#pragma unroll
    for (int i = 0; i < NL; ++i) {              // all loads in flight
      int idx8 = tid + i * 256;
      int r = idx8 / (KPAD / 8);
      int k = (idx8 - r * (KPAD / 8)) * 8;
      int gr = rowbase + r;
      vv[i] = (gr < NN) ? *(const bh8*)(in + (size_t)gr * KPAD + k) : bh8{};
    }
#pragma unroll
    for (int i = 0; i < NL; ++i) {
      int idx8 = tid + i * 256;
      int r = idx8 / (KPAD / 8);
      int k = (idx8 - r * (KPAD / 8)) * 8;
      bh8 v = vv[i];
      if (ss) {
#pragma unroll
        for (int j = 0; j < 8; ++j) {
          float f = bf2f((unsigned short)v[j]);
          f = fmaxf(fmaf(f, sss[k + j], sss[128 + k + j]), 0.f);
          v[j] = (short)f2bf(f);
        }
      }
      *(bh8*)&Alds[r * KL + k] = v;
    }
  } else {
    // fp32 slab staging: 64*DIN = 10560 consecutive floats, base 16B-aligned.
    const float* in = (const float*)in_;
    size_t slab = (size_t)rowbase * DIN;
    long rem = (long)NN * DIN - (long)slab;
    int lim4 = rem >= 10560 ? 2640 : (int)(rem >> 2);
    // zero pad columns [DIN, KPAD)
    for (int z = tid; z < 64 * (KPAD - DIN); z += 256) {
      int r = z / (KPAD - DIN), k = DIN + (z - r * (KPAD - DIN));
      Alds[r * KL + k] = 0;
    }
    float4 regs[11];
#pragma unroll
    for (int i = 0; i < 11; ++i) {              // independent, all in flight
      int idx4 = tid + i * 256;
      if (idx4 < lim4) regs[i] = *(const float4*)(in + slab + (size_t)idx4 * 4);
    }
#pragma unroll
    for (int i = 0; i < 11; ++i) {
      int idx4 = tid + i * 256;
      if (idx4 < lim4) {
        int e = idx4 * 4;
        int r = e / DIN, k = e - r * DIN;       // constexpr magic-mul
        float vv[4] = {regs[i].x, regs[i].y, regs[i].z, regs[i].w};
#pragma unroll
        for (int j = 0; j < 4; ++j) {
          Alds[r * KL + k] = f2bf(vv[j]);
          if (++k == DIN) { k = 0; ++r; }
        }
      }
    }
  }
  __syncthreads();

  int lane = tid & 63, wave = tid >> 6;
  int lr = lane & 15, lk = (lane >> 4) * 8;
  f4 acc[NCT] = {};
  for (int kt = 0; kt < KPAD / 32; ++kt) {
    bh8 a = *(const bh8*)&Alds[(wave * 16 + lr) * KL + kt * 32 + lk];
#pragma unroll
    for (int ct = 0; ct < NCT; ++ct) {
      bh8 b = *(const bh8*)&WT[(ct * 16 + lr) * KPAD + kt * 32 + lk];
      acc[ct] = __builtin_amdgcn_mfma_f32_16x16x32_bf16(a, b, acc[ct], 0, 0, 0);
    }
  }

  int r0 = rowbase + wave * 16 + (lane >> 4) * 4;
#pragma unroll
  for (int ct = 0; ct < NCT; ++ct) {
    int c = ct * 16 + lr;
    float bv = (bias != nullptr && c < C) ? bias[c] : 0.f;
    float cs = 0.f, cq = 0.f;
#pragma unroll
    for (int rg = 0; rg < 4; ++rg) {
      int gr = r0 + rg;
      if (gr < NN && c < C) {
        float v = acc[ct][rg] + bv;
        if (OUTBF) {
          unsigned short ub = f2bf(v);
          ((unsigned short*)out_)[(size_t)gr * C + c] = ub;
          v = bf2f(ub);  // stats on rounded value (matches consumer)
        } else {
          ((float*)out_)[(size_t)gr * C + c] = v;
        }
        cs += v; cq += v * v;
      }
    }
    if (stats && c < C) { atomicAdd(&s_sum[c], cs); atomicAdd(&s_sq[c], cq); }
  }
  if (stats) {
    __syncthreads();
    int slot = blockIdx.x & 63;
    if (tid < 128) {
      atomicAdd(&stats[slot * 256 + tid], s_sum[tid]);
      atomicAdd(&stats[slot * 256 + 128 + tid], s_sq[tid]);
    }
  }
}

// ---------- GCN aggregation (bf16 table) ----------
__global__ __launch_bounds__(256) void k_agg(const unsigned short* __restrict__ t, const int* __restrict__ colv,
                                             const int* __restrict__ rowptr, const int* __restrict__ deg,
                                             const float* __restrict__ dinv, unsigned short* __restrict__ out,
                                             float* __restrict__ stats) {
  __shared__ float rs[4][128], rq[4][128];
  int lane = threadIdx.x & 63, wave = threadIdx.x >> 6;
  int node = blockIdx.x * 4 + wave;
  float a0 = 0.f, a1 = 0.f;
  if (node < NN) {
    float di = dinv[node];
    uint32_t sv = *(const uint32_t*)(t + (size_t)node * 128 + lane * 2);
    a0 = di * di * bflo(sv); a1 = di * di * bfhi(sv);
    int start = rowptr[node], len = deg[node];
    for (int j0 = 0; j0 < len; j0 += 64) {
      int cnt = min(len - j0, 64);
      int id = 0; float dv = 0.f;
      if (lane < cnt) { id = colv[start + j0 + lane]; dv = dinv[id]; }
      int j = 0;
      for (; j + 4 <= cnt; j += 4) {  // 4 row-loads in flight
        int s0 = __shfl(id, j),     s1 = __shfl(id, j + 1);
        int s2 = __shfl(id, j + 2), s3 = __shfl(id, j + 3);
        float c0 = __shfl(dv, j) * di,     c1 = __shfl(dv, j + 1) * di;
        float c2 = __shfl(dv, j + 2) * di, c3 = __shfl(dv, j + 3) * di;
        uint32_t v0 = *(const uint32_t*)(t + (size_t)s0 * 128 + lane * 2);
        uint32_t v1 = *(const uint32_t*)(t + (size_t)s1 * 128 + lane * 2);
        uint32_t v2 = *(const uint32_t*)(t + (size_t)s2 * 128 + lane * 2);
        uint32_t v3 = *(const uint32_t*)(t + (size_t)s3 * 128 + lane * 2);
        a0 = fmaf(c0, bflo(v0), a0); a1 = fmaf(c0, bfhi(v0), a1);
        a0 = fmaf(c1, bflo(v1), a0); a1 = fmaf(c1, bfhi(v1), a1);
        a0 = fmaf(c2, bflo(v2), a0); a1 = fmaf(c2, bfhi(v2), a1);
        a0 = fmaf(c3, bflo(v3), a0); a1 = fmaf(c3, bfhi(v3), a1);
      }
      for (; j < cnt; ++j) {
        int s = __shfl(id, j);
        float c = __shfl(dv, j) * di;
        uint32_t v = *(const uint32_t*)(t + (size_t)s * 128 + lane * 2);
        a0 = fmaf(c, bflo(v), a0); a1 = fmaf(c, bfhi(v), a1);
      }
    }
    unsigned short u0 = f2bf(a0), u1 = f2bf(a1);
    *(uint32_t*)(out + (size_t)node * 128 + lane * 2) = (uint32_t)u0 | ((uint32_t)u1 << 16);
    a0 = bf2f(u0); a1 = bf2f(u1);  // stats on rounded values
  }
  rs[wave][lane * 2] = a0; rs[wave][lane * 2 + 1] = a1;
  rq[wave][lane * 2] = a0 * a0; rq[wave][lane * 2 + 1] = a1 * a1;
  __syncthreads();
  if (threadIdx.x < 128) {
    int c = threadIdx.x;
    float s = rs[0][c] + rs[1][c] + rs[2][c] + rs[3][c];
    float q = rq[0][c] + rq[1][c] + rq[2][c] + rq[3][c];
    int slot = blockIdx.x & 63;
    atomicAdd(&stats[slot * 256 + c], s);
    atomicAdd(&stats[slot * 256 + 128 + c], q);
  }
}

// ---------- BN finalize ----------
__global__ __launch_bounds__(128) void k_finalize(const float* __restrict__ stats, const float* __restrict__ g,
                                                  const float* __restrict__ be, float* __restrict__ ssout, int C) {
  int c = threadIdx.x;
  if (c < C) {
    float s = 0.f, q = 0.f;
    for (int k = 0; k < 64; ++k) { s += stats[k * 256 + c]; q += stats[k * 256 + 128 + c]; }
    const float invN = 1.f / (float)NN;
    float mean = s * invN;
    float var = fmaxf(q * invN - mean * mean, 0.f);
    float scale = g[c] * rsqrtf(var + 1e-5f);
    ssout[c] = scale;
    ssout[128 + c] = be[c] - mean * scale;
  }
}

// ---------- emb = relu(bn(a2)): fp32 to d_out AND bf16 copy for heads ----------
__global__ __launch_bounds__(256) void k_embwrite(const unsigned short* __restrict__ a2h,
                                                  const float* __restrict__ ss,
                                                  float* __restrict__ emb, unsigned short* __restrict__ embh) {
  int idx = blockIdx.x * 256 + threadIdx.x;  // 4 cols per thread
  if (idx < NN * 32) {
    int cb = (idx & 31) * 4;
    uint2 v = *(const uint2*)(a2h + (size_t)idx * 4);
    float f0 = fmaxf(fmaf(bflo(v.x), ss[cb],     ss[128 + cb]), 0.f);
    float f1 = fmaxf(fmaf(bfhi(v.x), ss[cb + 1], ss[129 + cb]), 0.f);
    float f2 = fmaxf(fmaf(bflo(v.y), ss[cb + 2], ss[130 + cb]), 0.f);
    float f3 = fmaxf(fmaf(bfhi(v.y), ss[cb + 3], ss[131 + cb]), 0.f);
    *(float4*)(emb + (size_t)idx * 4) = make_float4(f0, f1, f2, f3);
    uint2 o;
    o.x = (uint32_t)f2bf(f0) | ((uint32_t)f2bf(f1) << 16);
    o.y = (uint32_t)f2bf(f2) | ((uint32_t)f2bf(f3) << 16);
    *(uint2*)(embh + (size_t)idx * 4) = o;
  }
}

extern "C" void kernel_launch(void* const* d_in, const int* in_sizes, int n_in,
                              void* d_out, int out_size, void* d_ws, size_t ws_size,
                              hipStream_t stream) {
  (void)in_sizes; (void)n_in; (void)out_size; (void)ws_size;
  const float* x   = (const float*)d_in[0];
  const int*   ei  = (const int*)d_in[1];
  const float* W1  = (const float*)d_in[2];
  const float* W2  = (const float*)d_in[4];
  const float* g1  = (const float*)d_in[6];
  const float* be1 = (const float*)d_in[7];
  const float* g2  = (const float*)d_in[8];
  const float* be2 = (const float*)d_in[9];
  const float* fW1 = (const float*)d_in[10];
  const float* fg1 = (const float*)d_in[12];
  const float* fbe1= (const float*)d_in[13];
  const float* fW2 = (const float*)d_in[14];
  const float* fg2 = (const float*)d_in[16];
  const float* fbe2= (const float*)d_in[17];
  const float* fW3 = (const float*)d_in[18];
  const float* fb3 = (const float*)d_in[19];
  const float* bW1 = (const float*)d_in[20];
  const float* bg1 = (const float*)d_in[22];
  const float* bbe1= (const float*)d_in[23];
  const float* bW2 = (const float*)d_in[24];
  const float* bb2 = (const float*)d_in[25];

  float* outp = (float*)d_out;
  float* fl  = outp;                       // [NN,50]
  float* bl  = outp + (size_t)NN * 50;     // [NN,3]
  float* emb = outp + (size_t)NN * 53;     // [NN,128]

  char* wsb = (char*)d_ws;
  int*   deg    = (int*)(wsb + OFF_DEG);
  float* stats  = (float*)(wsb + OFF_STATS);
  int*   rowptr = (int*)(wsb + OFF_ROWPTR);
  int*   fillp  = (int*)(wsb + OFF_FILLP);
  float* dinv   = (float*)(wsb + OFF_DINV);
  int*   blk    = (int*)(wsb + OFF_BLK);
  float* ssb    = (float*)(wsb + OFF_SS);
  const unsigned short* W1T  = (const unsigned short*)(wsb + OFF_W1T);
  const unsigned short* W2T  = (const unsigned short*)(wsb + OFF_W2T);
  const unsigned short* FW1T = (const unsigned short*)(wsb + OFF_FW1T);
  const unsigned short* FW2T = (const unsigned short*)(wsb + OFF_FW2T);
  const unsigned short* FW3T = (const unsigned short*)(wsb + OFF_FW3T);
  const unsigned short* BW1T = (const unsigned short*)(wsb + OFF_BW1T);
  const unsigned short* BW2T = (const unsigned short*)(wsb + OFF_BW2T);
  int*            colv = (int*)(wsb + OFF_COL);
  unsigned short* buf0 = (unsigned short*)(wsb + OFF_BUF0);
  unsigned short* buf1 = (unsigned short*)(wsb + OFF_BUF1);
  unsigned short* buf2 = (unsigned short*)(wsb + OFF_BUF2);

  const int GG = (NN + 63) / 64;       // 1563
  const int GA = (NN + 3) / 4;         // 25000
  const int GP = 1024;                 // partitioned CSR kernels: 128 blocks/partition

  hipMemsetAsync(d_ws, 0, ZERO_BYTES, stream);  // deg + stats

  // CSR (dst-major, dst-partitioned) + dinv
  k_hist <<<GP, 256, 0, stream>>>(ei + NE, deg);
  k_scan1<<<NBS, 256, 0, stream>>>(deg, blk);
  k_scan2<<<1, 512, 0, stream>>>(blk);
  k_scan3<<<NBS, 256, 0, stream>>>(deg, blk, rowptr, fillp, dinv);
  k_fill <<<GP, 256, 0, stream>>>(ei, ei + NE, fillp, colv);
  k_wprep<<<308, 256, 0, stream>>>(W1, W2, fW1, fW2, fW3, bW1, bW2, wsb);

  // GCN layer 1: t1 = x@W1 ; a1 = A_hat t1 ; bn1
  k_gemm<192, 128, false, true><<<GG, 256, 0, stream>>>(x, DIN, 128, nullptr, W1T, nullptr, buf0, nullptr);
  k_agg<<<GA, 256, 0, stream>>>(buf0, colv, rowptr, deg, dinv, buf1, stats + 0 * 16384);
  k_finalize<<<1, 128, 0, stream>>>(stats + 0 * 16384, g1, be1, ssb + 0 * 256, 128);

  // GCN layer 2: t2 = relu(bn1(a1))@W2 ; a2 = A_hat t2 ; bn2
  k_gemm<128, 128, true, true><<<GG, 256, 0, stream>>>(buf1, 128, 128, ssb + 0 * 256, W2T, nullptr, buf0, nullptr);
  k_agg<<<GA, 256, 0, stream>>>(buf0, colv, rowptr, deg, dinv, buf1, stats + 1 * 16384);
  k_finalize<<<1, 128, 0, stream>>>(stats + 1 * 16384, g2, be2, ssb + 1 * 256, 128);

  // emb = relu(bn2(a2)) -> d_out fp32 + bf16 copy
  k_embwrite<<<NN * 32 / 256, 256, 0, stream>>>(buf1, ssb + 1 * 256, emb, buf2);

  // forward head
  k_gemm<128, 128, true, true><<<GG, 256, 0, stream>>>(buf2, 128, 128, nullptr, FW1T, nullptr, buf0, stats + 2 * 16384);
  k_finalize<<<1, 128, 0, stream>>>(stats + 2 * 16384, fg1, fbe1, ssb + 2 * 256, 128);
  k_gemm<128, 64, true, true><<<GG, 256, 0, stream>>>(buf0, 128, 64, ssb + 2 * 256, FW2T, nullptr, buf1, stats + 3 * 16384);
  k_finalize<<<1, 128, 0, stream>>>(stats + 3 * 16384, fg2, fbe2, ssb + 3 * 256, 64);
  k_gemm<64, 64, true, false><<<GG, 256, 0, stream>>>(buf1, 64, 50, ssb + 3 * 256, FW3T, fb3, fl, nullptr);

  // backward head
  k_gemm<128, 64, true, true><<<GG, 256, 0, stream>>>(buf2, 128, 64, nullptr, BW1T, nullptr, buf0, stats + 4 * 16384);
  k_finalize<<<1, 128, 0, stream>>>(stats + 4 * 16384, bg1, bbe1, ssb + 4 * 256, 64);
  k_gemm<64, 16, true, false><<<GG, 256, 0, stream>>>(buf0, 64, 3, ssb + 4 * 256, BW2T, bb2, bl, nullptr);
}